// Round 1
// baseline (743.681 us; speedup 1.0000x reference)
//
#include <hip/hip_runtime.h>

// BottleneckA: out = relu(W3·relu(g∘(W2·relu(g∘(W1·x+b1))+b2))+b3) + x
// x:[16,1024,56,56] f32, gate:[16,256], W1:[256,1024], W2:[256,256], W3:[1024,256]
//
// Strategy: bf16 MFMA GEMMs (16x16x32), fp32 accumulate. On-the-fly f32->bf16
// conversion in LDS staging. Intermediates h1,h2 (bf16, 25.7 MB each) in d_ws.
// Tile 128x128, 256 threads = 4 waves, each wave 64x64 via 4x4 MFMA frags.

#define NPIX 3136
#define BATCH 16
#define BM 128
#define BN 128
#define BK 32
#define ASTRIDE (BK + 8)   // +8 bf16 pad -> 80B row stride, 16B-aligned, 2-way-max banks

typedef __attribute__((ext_vector_type(8))) short short8;
typedef __attribute__((ext_vector_type(4))) float v4f;

__device__ __forceinline__ unsigned short f2bf(float f) {
    union { float f; unsigned u; } v; v.f = f;
    unsigned r = v.u + 0x7fffu + ((v.u >> 16) & 1u);
    return (unsigned short)(r >> 16);
}

// Y[b,o,n] = act over K: sum_k Wt[o,k] * Xin[b,k,n]
// GATED: y = relu((acc+bias)*relu(gate));  RES: y = relu(acc+bias) + xres (f32 out)
template<int M, int K, bool IN_BF16, bool GATED, bool RES>
__global__ __launch_bounds__(256, 2) void gemm_fused(
    const void* __restrict__ Xin, const float* __restrict__ Wt,
    const float* __restrict__ bias, const float* __restrict__ gate,
    const float* __restrict__ xres, void* __restrict__ Yout)
{
    __shared__ __attribute__((aligned(16))) unsigned short Asm[BM * ASTRIDE]; // [128][40]
    __shared__ __attribute__((aligned(16))) unsigned short Bsm[(BK / 8) * BN * 8]; // [4][128][8]

    const int b    = blockIdx.z;
    const int m0   = blockIdx.y * BM;
    const int n0   = blockIdx.x * BN;
    const int t    = threadIdx.x;
    const int lane = t & 63;
    const int wave = t >> 6;
    const int wm   = (wave >> 1) * 64;   // wave row offset in tile
    const int wn   = (wave & 1) * 64;    // wave col offset in tile
    const int l15  = lane & 15;
    const int quad = lane >> 4;

    v4f acc[4][4];
    #pragma unroll
    for (int i = 0; i < 4; ++i)
        #pragma unroll
        for (int j = 0; j < 4; ++j)
            acc[i][j] = (v4f){0.f, 0.f, 0.f, 0.f};

    // A-staging thread mapping: 32 rows x 8 k-quads per pass, 4 passes
    const int arb = t >> 3;          // 0..31
    const int akq = (t & 7) * 4;     // 0,4,...,28
    // B-staging thread mapping: 128 n x 2 k-octets per pass, 2 passes
    const int bnl = t & 127;
    int bng = n0 + bnl; if (bng > NPIX - 1) bng = NPIX - 1; // clamp (dup read, store-guarded)

    for (int k0 = 0; k0 < K; k0 += BK) {
        __syncthreads();
        // ---- stage A: Wt[m0..m0+127][k0..k0+31] f32 -> bf16 ----
        #pragma unroll
        for (int rr = 0; rr < 4; ++rr) {
            int row = rr * 32 + arb;
            const float4 w4 = *reinterpret_cast<const float4*>(
                &Wt[(size_t)(m0 + row) * K + k0 + akq]);
            unsigned p0 = (unsigned)f2bf(w4.x) | ((unsigned)f2bf(w4.y) << 16);
            unsigned p1 = (unsigned)f2bf(w4.z) | ((unsigned)f2bf(w4.w) << 16);
            *reinterpret_cast<uint2*>(&Asm[row * ASTRIDE + akq]) = make_uint2(p0, p1);
        }
        // ---- stage B: Xin[b][k0..k0+31][n0..n0+127] -> k-octet-packed bf16 ----
        #pragma unroll
        for (int oo = 0; oo < 2; ++oo) {
            int oct = (t >> 7) + oo * 2;   // 0..3
            int kb  = k0 + oct * 8;
            unsigned short e[8];
            #pragma unroll
            for (int j = 0; j < 8; ++j) {
                if (IN_BF16)
                    e[j] = reinterpret_cast<const unsigned short*>(Xin)
                               [((size_t)b * K + kb + j) * NPIX + bng];
                else
                    e[j] = f2bf(reinterpret_cast<const float*>(Xin)
                               [((size_t)b * K + kb + j) * NPIX + bng]);
            }
            uint4 p;
            p.x = (unsigned)e[0] | ((unsigned)e[1] << 16);
            p.y = (unsigned)e[2] | ((unsigned)e[3] << 16);
            p.z = (unsigned)e[4] | ((unsigned)e[5] << 16);
            p.w = (unsigned)e[6] | ((unsigned)e[7] << 16);
            *reinterpret_cast<uint4*>(&Bsm[(oct * BN + bnl) * 8]) = p;
        }
        __syncthreads();
        // ---- fragments + 16 MFMA ----
        short8 af[4], bf[4];
        #pragma unroll
        for (int mt = 0; mt < 4; ++mt)
            af[mt] = *reinterpret_cast<const short8*>(
                &Asm[(wm + mt * 16 + l15) * ASTRIDE + quad * 8]);
        #pragma unroll
        for (int nt = 0; nt < 4; ++nt)
            bf[nt] = *reinterpret_cast<const short8*>(
                &Bsm[(quad * BN + (wn + nt * 16 + l15)) * 8]);
        #pragma unroll
        for (int mt = 0; mt < 4; ++mt)
            #pragma unroll
            for (int nt = 0; nt < 4; ++nt)
                acc[mt][nt] = __builtin_amdgcn_mfma_f32_16x16x32_bf16(
                    af[mt], bf[nt], acc[mt][nt], 0, 0, 0);
    }

    // ---- epilogue: D[row=quad*4+r][col=l15] ----
    #pragma unroll
    for (int mt = 0; mt < 4; ++mt) {
        float bia[4], gg[4];
        #pragma unroll
        for (int r = 0; r < 4; ++r) {
            int o = m0 + wm + mt * 16 + quad * 4 + r;
            bia[r] = bias[o];
            if (GATED) {
                float g = gate[b * 256 + o];
                gg[r] = g > 0.f ? g : 0.f;
            }
        }
        #pragma unroll
        for (int nt = 0; nt < 4; ++nt) {
            int n = n0 + wn + nt * 16 + l15;
            if (n < NPIX) {
                #pragma unroll
                for (int r = 0; r < 4; ++r) {
                    int o = m0 + wm + mt * 16 + quad * 4 + r;
                    float v = acc[mt][nt][r] + bia[r];
                    if (GATED) v *= gg[r];
                    v = v > 0.f ? v : 0.f;
                    if (RES) {
                        v += xres[((size_t)b * 1024 + o) * NPIX + n];
                        reinterpret_cast<float*>(Yout)[((size_t)b * M + o) * NPIX + n] = v;
                    } else {
                        reinterpret_cast<unsigned short*>(Yout)
                            [((size_t)b * M + o) * NPIX + n] = f2bf(v);
                    }
                }
            }
        }
    }
}

extern "C" void kernel_launch(void* const* d_in, const int* in_sizes, int n_in,
                              void* d_out, int out_size, void* d_ws, size_t ws_size,
                              hipStream_t stream) {
    const float* x    = (const float*)d_in[0];
    const float* gate = (const float*)d_in[1];
    const float* W1   = (const float*)d_in[2];
    const float* b1   = (const float*)d_in[3];
    const float* W2   = (const float*)d_in[4];
    const float* b2   = (const float*)d_in[5];
    const float* W3   = (const float*)d_in[6];
    const float* b3   = (const float*)d_in[7];
    float* out = (float*)d_out;

    // ws: h1, h2 bf16 [16][256][3136] = 25.7 MB each (51.4 MB total)
    unsigned short* h1 = (unsigned short*)d_ws;
    unsigned short* h2 = h1 + (size_t)BATCH * 256 * NPIX;

    dim3 blk(256);
    const int ntiles = (NPIX + BN - 1) / BN;  // 25

    gemm_fused<256, 1024, false, true, false>
        <<<dim3(ntiles, 256 / BM, BATCH), blk, 0, stream>>>(x, W1, b1, gate, nullptr, h1);
    gemm_fused<256, 256, true, true, false>
        <<<dim3(ntiles, 256 / BM, BATCH), blk, 0, stream>>>(h1, W2, b2, gate, nullptr, h2);
    gemm_fused<1024, 256, true, false, true>
        <<<dim3(ntiles, 1024 / BM, BATCH), blk, 0, stream>>>(h2, W3, b3, nullptr, x, out);
}

// Round 2
// 553.546 us; speedup vs baseline: 1.3435x; 1.3435x over previous
//
#include <hip/hip_runtime.h>

// BottleneckA: out = relu(W3·relu(g∘(W2·relu(g∘(W1·x+b1))+b2))+b3) + x
// x:[16,1024,56,56] f32, gate:[16,256], W1:[256,1024], W2:[256,256], W3:[1024,256]
//
// m97-structure MFMA GEMMs: all operands k-contiguous bf16, staged via
// global_load_lds(16B), frags via ds_read_b128, 16x16x32 bf16 MFMA.
// Pre-pass: W->bf16, x->xT [b][n][c] bf16. h1/h2 in [b][pix][o] (A-layout).

#define NPIX 3136
#define BATCH 16

typedef __attribute__((ext_vector_type(8))) short short8;
typedef __attribute__((ext_vector_type(4))) float v4f;

__device__ __forceinline__ unsigned short f2bf(float f) {
    union { float f; unsigned u; } v; v.f = f;
    unsigned r = v.u + 0x7fffu + ((v.u >> 16) & 1u);
    return (unsigned short)(r >> 16);
}

__device__ __forceinline__ void ld_g2l16(const unsigned short* g, unsigned short* l) {
    __builtin_amdgcn_global_load_lds(
        (const __attribute__((address_space(1))) unsigned int*)g,
        (__attribute__((address_space(3))) unsigned int*)l,
        16, 0, 0);
}

// ---- W f32 -> bf16 (concatenated W1|W2|W3), 4 elems/thread ----
__global__ void convert_w(const float* __restrict__ W1, const float* __restrict__ W2,
                          const float* __restrict__ W3, unsigned short* __restrict__ Wb) {
    size_t e = ((size_t)blockIdx.x * 256 + threadIdx.x) * 4;
    const float* src; size_t off;
    if (e < 262144)      { src = W1; off = e; }
    else if (e < 327680) { src = W2; off = e - 262144; }
    else                 { src = W3; off = e - 327680; }
    float4 v = *reinterpret_cast<const float4*>(&src[off]);
    uint2 p;
    p.x = (unsigned)f2bf(v.x) | ((unsigned)f2bf(v.y) << 16);
    p.y = (unsigned)f2bf(v.z) | ((unsigned)f2bf(v.w) << 16);
    *reinterpret_cast<uint2*>(&Wb[e]) = p;
}

// ---- x [b][c 1024][n 3136] f32 -> xT [b][n][c] bf16, 64x64 LDS tiles ----
__global__ __launch_bounds__(256) void transpose_x(const float* __restrict__ x,
                                                   unsigned short* __restrict__ xT) {
    __shared__ unsigned short T[64][72];  // [c][n], +8 pad
    const int b = blockIdx.z, c0 = blockIdx.y * 64, n0 = blockIdx.x * 64;
    const int t = threadIdx.x;
    {   // load: thread = (c = t>>2, 16 n starting at (t&3)*16)
        const int c = t >> 2, nc = (t & 3) * 16;
        const float* src = &x[((size_t)(b * 1024 + c0 + c)) * NPIX + n0 + nc];
        #pragma unroll
        for (int j = 0; j < 4; ++j) {
            float4 v = *reinterpret_cast<const float4*>(&src[j * 4]);
            uint2 p;
            p.x = (unsigned)f2bf(v.x) | ((unsigned)f2bf(v.y) << 16);
            p.y = (unsigned)f2bf(v.z) | ((unsigned)f2bf(v.w) << 16);
            *reinterpret_cast<uint2*>(&T[c][nc + j * 4]) = p;
        }
    }
    __syncthreads();
    {   // store: thread = (n = t>>3 (+32), 8 c starting at (t&7)*8) -> uint4
        const int cc = (t & 7) * 8;
        #pragma unroll
        for (int pass = 0; pass < 2; ++pass) {
            const int n = (t >> 3) + pass * 32;
            uint4 u;
            u.x = (unsigned)T[cc + 0][n] | ((unsigned)T[cc + 1][n] << 16);
            u.y = (unsigned)T[cc + 2][n] | ((unsigned)T[cc + 3][n] << 16);
            u.z = (unsigned)T[cc + 4][n] | ((unsigned)T[cc + 5][n] << 16);
            u.w = (unsigned)T[cc + 6][n] | ((unsigned)T[cc + 7][n] << 16);
            *reinterpret_cast<uint4*>(
                &xT[((size_t)(b * NPIX + n0 + n)) * 1024 + c0 + cc]) = u;
        }
    }
}

// ---- GEMM: D-tile 128(rows) x 128(cols); ROWS_PIX picks orientation ----
// Xact: [b][pix][K] bf16 ; Wgt: [M][K] bf16
// !ROWS_PIX (L1/L2): rows=o, cols=pix -> bf16 Y [b][pix][M] gated-relu
//  ROWS_PIX (L3):    rows=pix, cols=o -> f32  Y [b][M][NPIX] relu + residual
template<int K, int M, bool ROWS_PIX, bool GATED, bool RES>
__global__ __launch_bounds__(256, 2) void gemm_fused(
    const unsigned short* __restrict__ Xact, const unsigned short* __restrict__ Wgt,
    const float* __restrict__ bias, const float* __restrict__ gate,
    const float* __restrict__ xres, void* __restrict__ Yout)
{
    __shared__ __attribute__((aligned(16))) unsigned short Xsm[128 * 32]; // [pix][k]
    __shared__ __attribute__((aligned(16))) unsigned short Wsm[128 * 32]; // [o][k]

    const int b  = blockIdx.z;
    const int o0 = blockIdx.y * 128;
    const int p0 = blockIdx.x * 128;
    const int t    = threadIdx.x;
    const int lane = t & 63;
    const int wave = t >> 6;
    const int wm   = (wave >> 1) * 64;
    const int wn   = (wave & 1) * 64;
    const int l15  = lane & 15;
    const int quad = lane >> 4;

    v4f acc[4][4];
    #pragma unroll
    for (int i = 0; i < 4; ++i)
        #pragma unroll
        for (int j = 0; j < 4; ++j)
            acc[i][j] = (v4f){0.f, 0.f, 0.f, 0.f};

    // staging: thread t covers 16B = row t>>2 (+64), k-offset (t&3)*8
    const int srow  = t >> 2;
    const int skoff = (t & 3) * 8;
    int pr0 = p0 + srow;      if (pr0 > NPIX - 1) pr0 = NPIX - 1;
    int pr1 = p0 + srow + 64; if (pr1 > NPIX - 1) pr1 = NPIX - 1;
    const unsigned short* xg0 = Xact + ((size_t)(b * NPIX + pr0)) * K + skoff;
    const unsigned short* xg1 = Xact + ((size_t)(b * NPIX + pr1)) * K + skoff;
    const unsigned short* wg0 = Wgt + ((size_t)(o0 + srow)) * K + skoff;
    const unsigned short* wg1 = Wgt + ((size_t)(o0 + srow + 64)) * K + skoff;

    for (int k0 = 0; k0 < K; k0 += 32) {
        __syncthreads();
        ld_g2l16(xg0 + k0, &Xsm[t * 8]);
        ld_g2l16(xg1 + k0, &Xsm[2048 + t * 8]);
        ld_g2l16(wg0 + k0, &Wsm[t * 8]);
        ld_g2l16(wg1 + k0, &Wsm[2048 + t * 8]);
        __syncthreads();

        const unsigned short* RowLds = ROWS_PIX ? Xsm : Wsm;
        const unsigned short* ColLds = ROWS_PIX ? Wsm : Xsm;
        short8 rf[4], cf[4];
        #pragma unroll
        for (int mt = 0; mt < 4; ++mt)
            rf[mt] = *reinterpret_cast<const short8*>(
                &RowLds[(wm + mt * 16 + l15) * 32 + quad * 8]);
        #pragma unroll
        for (int nt = 0; nt < 4; ++nt)
            cf[nt] = *reinterpret_cast<const short8*>(
                &ColLds[(wn + nt * 16 + l15) * 32 + quad * 8]);
        #pragma unroll
        for (int mt = 0; mt < 4; ++mt)
            #pragma unroll
            for (int nt = 0; nt < 4; ++nt)
                acc[mt][nt] = __builtin_amdgcn_mfma_f32_16x16x32_bf16(
                    rf[mt], cf[nt], acc[mt][nt], 0, 0, 0);
    }

    if (!ROWS_PIX) {
        // rows = o (quad*4+r consecutive), cols = pix. Y: bf16 [b][pix][M]
        unsigned short* Yh = reinterpret_cast<unsigned short*>(Yout);
        #pragma unroll
        for (int mt = 0; mt < 4; ++mt) {
            const int o = o0 + wm + mt * 16 + quad * 4;
            const float4 bi = *reinterpret_cast<const float4*>(&bias[o]);
            float g0 = 1.f, g1 = 1.f, g2 = 1.f, g3 = 1.f;
            if (GATED) {
                float4 gv = *reinterpret_cast<const float4*>(&gate[b * 256 + o]);
                g0 = gv.x > 0.f ? gv.x : 0.f; g1 = gv.y > 0.f ? gv.y : 0.f;
                g2 = gv.z > 0.f ? gv.z : 0.f; g3 = gv.w > 0.f ? gv.w : 0.f;
            }
            #pragma unroll
            for (int nt = 0; nt < 4; ++nt) {
                const int pix = p0 + wn + nt * 16 + l15;
                if (pix < NPIX) {
                    float v0 = acc[mt][nt][0] + bi.x, v1 = acc[mt][nt][1] + bi.y;
                    float v2 = acc[mt][nt][2] + bi.z, v3 = acc[mt][nt][3] + bi.w;
                    if (GATED) { v0 *= g0; v1 *= g1; v2 *= g2; v3 *= g3; }
                    v0 = v0 > 0.f ? v0 : 0.f; v1 = v1 > 0.f ? v1 : 0.f;
                    v2 = v2 > 0.f ? v2 : 0.f; v3 = v3 > 0.f ? v3 : 0.f;
                    uint2 p;
                    p.x = (unsigned)f2bf(v0) | ((unsigned)f2bf(v1) << 16);
                    p.y = (unsigned)f2bf(v2) | ((unsigned)f2bf(v3) << 16);
                    *reinterpret_cast<uint2*>(&Yh[((size_t)(b * NPIX + pix)) * M + o]) = p;
                }
            }
        }
    } else {
        // rows = pix (quad*4+r consecutive), cols = o. Y: f32 [b][M][NPIX] + x
        float* Yf = reinterpret_cast<float*>(Yout);
        #pragma unroll
        for (int nt = 0; nt < 4; ++nt) {
            const int o = o0 + wn + nt * 16 + l15;
            const float bi = bias[o];
            #pragma unroll
            for (int mt = 0; mt < 4; ++mt) {
                const int pix = p0 + wm + mt * 16 + quad * 4;
                if (pix < NPIX) {
                    const size_t base = ((size_t)(b * M + o)) * NPIX + pix;
                    float4 xr = *reinterpret_cast<const float4*>(&xres[base]);
                    float4 ov;
                    float v0 = acc[mt][nt][0] + bi, v1 = acc[mt][nt][1] + bi;
                    float v2 = acc[mt][nt][2] + bi, v3 = acc[mt][nt][3] + bi;
                    ov.x = (v0 > 0.f ? v0 : 0.f) + xr.x;
                    ov.y = (v1 > 0.f ? v1 : 0.f) + xr.y;
                    ov.z = (v2 > 0.f ? v2 : 0.f) + xr.z;
                    ov.w = (v3 > 0.f ? v3 : 0.f) + xr.w;
                    *reinterpret_cast<float4*>(&Yf[base]) = ov;
                }
            }
        }
    }
}

extern "C" void kernel_launch(void* const* d_in, const int* in_sizes, int n_in,
                              void* d_out, int out_size, void* d_ws, size_t ws_size,
                              hipStream_t stream) {
    const float* x    = (const float*)d_in[0];
    const float* gate = (const float*)d_in[1];
    const float* W1   = (const float*)d_in[2];
    const float* b1   = (const float*)d_in[3];
    const float* W2   = (const float*)d_in[4];
    const float* b2   = (const float*)d_in[5];
    const float* W3   = (const float*)d_in[6];
    const float* b3   = (const float*)d_in[7];
    float* out = (float*)d_out;

    // ws layout (bytes): xT 102,760,448 | h1 25,690,112 | Wb 1,179,648
    // h2 aliases the xT region (xT dead after L1).
    unsigned short* xT = (unsigned short*)d_ws;
    unsigned short* h1 = xT + (size_t)BATCH * NPIX * 1024;
    unsigned short* Wb = h1 + (size_t)BATCH * NPIX * 256;
    unsigned short* h2 = xT;  // alias
    unsigned short* W1b = Wb;
    unsigned short* W2b = Wb + 262144;
    unsigned short* W3b = Wb + 327680;

    dim3 blk(256);
    convert_w<<<576, blk, 0, stream>>>(W1, W2, W3, Wb);
    transpose_x<<<dim3(49, 16, BATCH), blk, 0, stream>>>(x, xT);
    gemm_fused<1024, 256, false, true, false>
        <<<dim3(25, 2, BATCH), blk, 0, stream>>>(xT, W1b, b1, gate, nullptr, h1);
    gemm_fused<256, 256, false, true, false>
        <<<dim3(25, 2, BATCH), blk, 0, stream>>>(h1, W2b, b2, gate, nullptr, h2);
    gemm_fused<256, 1024, true, false, true>
        <<<dim3(25, 8, BATCH), blk, 0, stream>>>(h2, W3b, b3, nullptr, x, out);
}